// Round 3
// baseline (237.503 us; speedup 1.0000x reference)
//
#include <hip/hip_runtime.h>
#include <math.h>

#define N_IMG 128
#define C_DIM 128
#define K_CL  64
#define S_PIX 4096
#define PB    8                 // blocks per image
#define SPB   (S_PIX/PB)        // 512 pixels per block
#define CHK   64                // pixels per chunk
#define NCHK  (SPB/CHK)         // 8
#define SROW  72                // a' row stride (bf16 elems) = 144B (rows 16B-aligned)
#define ASZ   (K_CL*SROW)       // one a' plane

typedef __attribute__((ext_vector_type(8))) short bf16x8;
typedef __attribute__((ext_vector_type(4))) float f32x4;

__device__ __forceinline__ unsigned short f2bf_rn(float v) {
    unsigned u = __float_as_uint(v);
    unsigned r = u + 0x7fffu + ((u >> 16) & 1u);
    return (unsigned short)(r >> 16);
}
__device__ __forceinline__ float bf2f(unsigned short h) {
    return __uint_as_float(((unsigned)h) << 16);
}

// truncation hi/lo split of 8 floats -> two bf16x8, packed via v_perm
__device__ __forceinline__ void cvt8(const float* v, bf16x8& h, bf16x8& l) {
    union { unsigned w[4]; bf16x8 v8; } H, L;
    #pragma unroll
    for (int p = 0; p < 4; ++p) {
        unsigned u0 = __float_as_uint(v[2*p]);
        unsigned u1 = __float_as_uint(v[2*p+1]);
        float r0 = v[2*p]   - __uint_as_float(u0 & 0xffff0000u);
        float r1 = v[2*p+1] - __uint_as_float(u1 & 0xffff0000u);
        H.w[p] = __builtin_amdgcn_perm(u1, u0, 0x07060302u);
        L.w[p] = __builtin_amdgcn_perm(__float_as_uint(r1), __float_as_uint(r0), 0x07060302u);
    }
    h = H.v8; l = L.v8;
}

// swizzled a'-tile index: 16B slots XOR'd by k to spread banks
__device__ __forceinline__ int as_idx(int k, int s) {
    return k * SROW + ((((s >> 3) ^ (k & 7)) << 3) | (s & 7));
}

// ---- kernel 0: W [K][C] fp32 -> pre-fragmented hi/lo bf16 A-fragments ----
__global__ void k_prep(const float* __restrict__ w, unsigned short* __restrict__ wf) {
    int i = blockIdx.x * 256 + threadIdx.x;          // 8192
    int j = i & 7, l = (i >> 3) & 63, t = (i >> 9) & 3, m = (i >> 11) & 3;
    int k = 16*m + (l & 15);
    int c = 32*t + ((l >> 4) << 3) + j;
    float v = w[k * C_DIM + c];
    unsigned short h = f2bf_rn(v);
    wf[i]        = h;
    wf[8192 + i] = f2bf_rn(v - bf2f(h));
}

// ---- kernel 1: fused GEMM1(MFMA) -> softmax -> GEMM2(MFMA), pipelined ----
__global__ __launch_bounds__(256, 3)
void k_main(const float* __restrict__ x,              // [N][C][S]
            const unsigned short* __restrict__ wf,    // [2][16][64][8] bf16 bits
            const float* __restrict__ bias,           // [K]
            float* __restrict__ vlad,                 // [N][K][C] accumulator (= d_out)
            float* __restrict__ asum)                 // [N][K]
{
    __shared__ f32x4 lWv[2048];                       // 32KB: W fragments hi/lo
    __shared__ f32x4 aSv[1152];                       // 18KB: a' tile (hi/lo planes)
    __shared__ float bias_s[64];                      // per-g bias table
    unsigned short* lW = (unsigned short*)lWv;
    unsigned short* aS = (unsigned short*)aSv;

    const int tid  = threadIdx.x;
    const int lane = tid & 63;
    const int wid  = tid >> 6;
    const int lc   = lane & 15;
    const int g    = lane >> 4;

    const int n  = blockIdx.x / PB;
    const int sp = blockIdx.x % PB;
    const float* xn = x + (size_t)n * (C_DIM * S_PIX) + sp * SPB;
    const int cq = wid * 32;

    // stage W fragments + bias table
    #pragma unroll
    for (int it = 0; it < 8; ++it)
        lWv[it*256 + tid] = ((const f32x4*)wf)[it*256 + tid];
    if (tid < 64) {
        int gg = tid >> 4, r = tid & 15;
        bias_s[tid] = bias[16*(r >> 2) + 4*gg + (r & 3)];
    }

    f32x4 accV[4][2];
    #pragma unroll
    for (int m = 0; m < 4; ++m) { accV[m][0] = (f32x4)0.f; accV[m][1] = (f32x4)0.f; }
    float asum_acc[16];
    #pragma unroll
    for (int i = 0; i < 16; ++i) asum_acc[i] = 0.f;

    float pa[32], pb[32];
    // prologue: phase-A x for chunk 0
    {
        const int sA = wid*16 + lc;
        #pragma unroll
        for (int t = 0; t < 4; ++t) {
            const float* xp = xn + (size_t)(32*t + 8*g) * S_PIX + sA;
            #pragma unroll
            for (int j = 0; j < 8; ++j) pa[t*8+j] = xp[(size_t)j * S_PIX];
        }
    }
    __syncthreads();

    for (int ch = 0; ch < NCHK; ++ch) {
        // ---- sumsq from pa, then convert pa -> fragments (pa dead after) ----
        float ss = 0.f;
        #pragma unroll
        for (int i = 0; i < 32; ++i) ss = fmaf(pa[i], pa[i], ss);
        bf16x8 bh[4], bl[4];
        #pragma unroll
        for (int t = 0; t < 4; ++t) cvt8(&pa[t*8], bh[t], bl[t]);

        // ---- issue NEXT chunk's phase-A loads (in flight across softmax+B) ----
        if (ch + 1 < NCHK) {
            const int sA = (ch+1)*CHK + wid*16 + lc;
            #pragma unroll
            for (int t = 0; t < 4; ++t) {
                const float* xp = xn + (size_t)(32*t + 8*g) * S_PIX + sA;
                #pragma unroll
                for (int j = 0; j < 8; ++j) pa[t*8+j] = xp[(size_t)j * S_PIX];
            }
        }
        // ---- issue THIS chunk's phase-B loads (in flight across phase A) ----
        #pragma unroll
        for (int ks = 0; ks < 2; ++ks)
            #pragma unroll
            for (int nn = 0; nn < 2; ++nn) {
                const float* xp = xn + (size_t)(cq + nn*16 + lc) * S_PIX
                                + ch*CHK + ks*32 + 8*g;
                float4 f0 = *(const float4*)xp;
                float4 f1 = *(const float4*)(xp + 4);
                int b = (ks*2 + nn) * 8;
                pb[b+0]=f0.x; pb[b+1]=f0.y; pb[b+2]=f0.z; pb[b+3]=f0.w;
                pb[b+4]=f1.x; pb[b+5]=f1.y; pb[b+6]=f1.z; pb[b+7]=f1.w;
            }

        // ---- GEMM1: logits (split-bf16, 3-term) ----
        f32x4 accL[4];
        #pragma unroll
        for (int m = 0; m < 4; ++m) accL[m] = (f32x4)0.f;
        #pragma unroll
        for (int t = 0; t < 4; ++t) {
            #pragma unroll
            for (int m = 0; m < 4; ++m) {
                bf16x8 ah = *(const bf16x8*)&lW[((m*4 + t)*64 + lane)*8];
                bf16x8 al = *(const bf16x8*)&lW[((16 + m*4 + t)*64 + lane)*8];
                accL[m] = __builtin_amdgcn_mfma_f32_16x16x32_bf16(ah, bh[t], accL[m], 0,0,0);
                accL[m] = __builtin_amdgcn_mfma_f32_16x16x32_bf16(ah, bl[t], accL[m], 0,0,0);
                accL[m] = __builtin_amdgcn_mfma_f32_16x16x32_bf16(al, bh[t], accL[m], 0,0,0);
            }
        }

        // ---- softmax over k=64 ----
        ss += __shfl_xor(ss, 16); ss += __shfl_xor(ss, 32);
        float rnorm = 1.0f / fmaxf(sqrtf(ss), 1e-12f);

        const f32x4* bt = (const f32x4*)&bias_s[g*16];
        f32x4 bb4[4];
        #pragma unroll
        for (int m = 0; m < 4; ++m) bb4[m] = bt[m];

        float e[16]; float mx = -1e30f;
        #pragma unroll
        for (int m = 0; m < 4; ++m)
            #pragma unroll
            for (int jj = 0; jj < 4; ++jj) {
                float t2 = fmaf(accL[m][jj], rnorm, bb4[m][jj]);
                e[m*4+jj] = t2;
                mx = fmaxf(mx, t2);
            }
        mx = fmaxf(mx, __shfl_xor(mx, 16)); mx = fmaxf(mx, __shfl_xor(mx, 32));
        float sm = 0.f;
        #pragma unroll
        for (int i = 0; i < 16; ++i) { e[i] = __expf(e[i] - mx); sm += e[i]; }
        sm += __shfl_xor(sm, 16); sm += __shfl_xor(sm, 32);
        float inv = 1.0f / sm;

        // ---- a' = a*rnorm -> hi/lo bf16 -> swizzled LDS tile ----
        const int sl = wid*16 + lc;
        #pragma unroll
        for (int m = 0; m < 4; ++m)
            #pragma unroll
            for (int jj = 0; jj < 4; ++jj) {
                float a = e[m*4+jj] * inv;
                asum_acc[m*4+jj] += a;
                float ap = a * rnorm;
                unsigned u = __float_as_uint(ap);
                unsigned short h = (unsigned short)(u >> 16);
                float r = ap - __uint_as_float(u & 0xffff0000u);
                int k = 16*m + 4*g + jj;
                int ix = as_idx(k, sl);
                aS[ix]       = h;
                aS[ASZ + ix] = (unsigned short)(__float_as_uint(r) >> 16);
            }
        __syncthreads();   // a' tile complete

        // ---- GEMM2: vlad partial (split-bf16, 3-term) ----
        #pragma unroll
        for (int ks = 0; ks < 2; ++ks) {
            bf16x8 Ah[4], Al[4];
            #pragma unroll
            for (int m = 0; m < 4; ++m) {
                int k = 16*m + lc;
                int off = k*SROW + (((4*ks + g) ^ (k & 7)) << 3);
                Ah[m] = *(const bf16x8*)&aS[off];
                Al[m] = *(const bf16x8*)&aS[ASZ + off];
            }
            #pragma unroll
            for (int nn = 0; nn < 2; ++nn) {
                bf16x8 xh, xl;
                cvt8(&pb[(ks*2 + nn)*8], xh, xl);
                #pragma unroll
                for (int m = 0; m < 4; ++m) {
                    accV[m][nn] = __builtin_amdgcn_mfma_f32_16x16x32_bf16(Ah[m], xh, accV[m][nn], 0,0,0);
                    accV[m][nn] = __builtin_amdgcn_mfma_f32_16x16x32_bf16(Ah[m], xl, accV[m][nn], 0,0,0);
                    accV[m][nn] = __builtin_amdgcn_mfma_f32_16x16x32_bf16(Al[m], xh, accV[m][nn], 0,0,0);
                }
            }
        }
        __syncthreads();   // aS free for next chunk
    }

    // ---- epilogue: vlad partials -> global atomics ----
    float* vb = vlad + (size_t)n * (K_CL * C_DIM);
    #pragma unroll
    for (int m = 0; m < 4; ++m)
        #pragma unroll
        for (int nn = 0; nn < 2; ++nn)
            #pragma unroll
            for (int jj = 0; jj < 4; ++jj)
                atomicAdd(&vb[(16*m + 4*g + jj)*C_DIM + cq + nn*16 + lc],
                          accV[m][nn][jj]);

    // ---- asum: 16-lane butterfly (lanes sharing g), then atomics ----
    #pragma unroll
    for (int i = 0; i < 16; ++i) {
        float v = asum_acc[i];
        v += __shfl_xor(v, 1); v += __shfl_xor(v, 2);
        v += __shfl_xor(v, 4); v += __shfl_xor(v, 8);
        asum_acc[i] = v;
    }
    if (lc == 0) {
        #pragma unroll
        for (int m = 0; m < 4; ++m)
            #pragma unroll
            for (int jj = 0; jj < 4; ++jj)
                atomicAdd(&asum[n*K_CL + 16*m + 4*g + jj], asum_acc[m*4+jj]);
    }
}

// ---- kernel 2: subtract a-sum*centroid, intra-norm, global norm ----
__global__ __launch_bounds__(256)
void k_final(float* __restrict__ vlad,          // [N][K*C] in/out (= d_out)
             const float* __restrict__ asum,    // [N][K]
             const float* __restrict__ cent)    // [K][C]
{
    __shared__ float v[K_CL * 132];
    __shared__ float red[K_CL][4];
    __shared__ float rin[K_CL];
    __shared__ float rtot_s;
    const int tid = threadIdx.x;
    const int n   = blockIdx.x;
    float* vb = vlad + (size_t)n * (K_CL * C_DIM);
    const float* as = asum + n * K_CL;

    for (int i = tid; i < K_CL*C_DIM; i += 256) {
        int k = i >> 7, c = i & 127;
        v[k*132 + c] = vb[i] - as[k] * cent[i];
    }
    __syncthreads();
    {
        int k = tid >> 2, p = tid & 3;
        float s2 = 0.f;
        #pragma unroll
        for (int u = 0; u < 32; ++u) { float t = v[k*132 + (u<<2) + p]; s2 = fmaf(t, t, s2); }
        red[k][p] = s2;
    }
    __syncthreads();
    if (tid < K_CL) {
        float s2 = red[tid][0] + red[tid][1] + red[tid][2] + red[tid][3];
        float r  = 1.0f / fmaxf(sqrtf(s2), 1e-12f);
        rin[tid] = r;
        red[tid][0] = s2 * r * r;
    }
    __syncthreads();
    if (tid < 64) {
        float t = red[tid][0];
        t += __shfl_xor(t, 32); t += __shfl_xor(t, 16); t += __shfl_xor(t, 8);
        t += __shfl_xor(t, 4);  t += __shfl_xor(t, 2);  t += __shfl_xor(t, 1);
        if (tid == 0) rtot_s = 1.0f / fmaxf(sqrtf(t), 1e-12f);
    }
    __syncthreads();
    float rt = rtot_s;
    for (int i = tid; i < K_CL*C_DIM; i += 256) {
        vb[i] = v[(i>>7)*132 + (i&127)] * rin[i>>7] * rt;
    }
}

extern "C" void kernel_launch(void* const* d_in, const int* in_sizes, int n_in,
                              void* d_out, int out_size, void* d_ws, size_t ws_size,
                              hipStream_t stream) {
    const float* x    = (const float*)d_in[0];
    const float* w    = (const float*)d_in[1];
    const float* b    = (const float*)d_in[2];
    const float* cent = (const float*)d_in[3];
    float* out = (float*)d_out;
    unsigned short* wf = (unsigned short*)d_ws;           // 32KB
    float* asum = (float*)((char*)d_ws + 32768);          // [N][K]

    hipMemsetAsync(out,  0, (size_t)N_IMG * K_CL * C_DIM * sizeof(float), stream);
    hipMemsetAsync(asum, 0, (size_t)N_IMG * K_CL * sizeof(float), stream);

    k_prep<<<32, 256, 0, stream>>>(w, wf);
    k_main<<<N_IMG * PB, 256, 0, stream>>>(x, wf, b, out, asum);
    k_final<<<N_IMG, 256, 0, stream>>>(out, asum, cent);
}

// Round 4
// 150.616 us; speedup vs baseline: 1.5769x; 1.5769x over previous
//
#include <hip/hip_runtime.h>
#include <math.h>

#define N_IMG 128
#define C_DIM 128
#define K_CL  64
#define S_PIX 4096
#define PB    8                 // blocks per image
#define SPB   (S_PIX/PB)        // 512 pixels per block
#define CHK   64                // pixels per chunk
#define NCHK  (SPB/CHK)         // 8
#define SROW  72                // a' row stride (bf16 elems) = 144B
#define ASZ   (K_CL*SROW)       // one a' plane

// 16B-slot XOR swizzle key for the X tile (involution; applied to global src AND reads)
#define KXOR(c) ((((c)&3)<<2) | (((c)>>2)&3))

typedef __attribute__((ext_vector_type(8))) short bf16x8;
typedef __attribute__((ext_vector_type(4))) float f32x4;

__device__ __forceinline__ unsigned short f2bf_rn(float v) {
    unsigned u = __float_as_uint(v);
    unsigned r = u + 0x7fffu + ((u >> 16) & 1u);
    return (unsigned short)(r >> 16);
}
__device__ __forceinline__ float bf2f(unsigned short h) {
    return __uint_as_float(((unsigned)h) << 16);
}

// truncation hi/lo split of 8 floats -> two bf16x8, packed via v_perm
__device__ __forceinline__ void cvt8(const float* v, bf16x8& h, bf16x8& l) {
    union { unsigned w[4]; bf16x8 v8; } H, L;
    #pragma unroll
    for (int p = 0; p < 4; ++p) {
        unsigned u0 = __float_as_uint(v[2*p]);
        unsigned u1 = __float_as_uint(v[2*p+1]);
        float r0 = v[2*p]   - __uint_as_float(u0 & 0xffff0000u);
        float r1 = v[2*p+1] - __uint_as_float(u1 & 0xffff0000u);
        H.w[p] = __builtin_amdgcn_perm(u1, u0, 0x07060302u);
        L.w[p] = __builtin_amdgcn_perm(__float_as_uint(r1), __float_as_uint(r0), 0x07060302u);
    }
    h = H.v8; l = L.v8;
}

// async global->LDS, 16B per lane, lane writes lds + lane*16 (linear)
__device__ __forceinline__ void gll16(const float* g, float* l) {
    __builtin_amdgcn_global_load_lds(
        (const __attribute__((address_space(1))) unsigned int*)(g),
        (__attribute__((address_space(3))) unsigned int*)(l),
        16, 0, 0);
}

// ---- kernel 0: W [K][C] fp32 -> pre-fragmented hi/lo bf16 A-fragments ----
// kdim map: MFMA kdim position p=8g+j (g=lane>>4) <-> channel c = 32t + 4j + g
__global__ void k_prep(const float* __restrict__ w, unsigned short* __restrict__ wf) {
    int i = blockIdx.x * 256 + threadIdx.x;          // 8192
    int j = i & 7, l = (i >> 3) & 63, t = (i >> 9) & 3, m = (i >> 11) & 3;
    int k = 16*m + (l & 15);
    int c = 32*t + 4*j + (l >> 4);
    float v = w[k * C_DIM + c];
    unsigned short h = f2bf_rn(v);
    wf[i]        = h;
    wf[8192 + i] = f2bf_rn(v - bf2f(h));
}

// ---- kernel 1: fused GEMM1(MFMA) -> softmax -> GEMM2(MFMA), async-staged ----
__global__ __launch_bounds__(256)
void k_main(const float* __restrict__ x,              // [N][C][S]
            const unsigned short* __restrict__ wf,    // [2][16][64][8] bf16 bits
            const float* __restrict__ bias,           // [K]
            float* __restrict__ vlad,                 // [N][K][C] accumulator (= d_out)
            float* __restrict__ asum)                 // [N][K]
{
    __shared__ float Xs[2][C_DIM*CHK];                // 64KB: x chunk tile, dbuf, swizzled
    __shared__ f32x4 lWv[2048];                       // 32KB: W fragments hi/lo
    __shared__ unsigned short aS[2*ASZ];              // 18KB: a' tile (hi/lo planes)
    __shared__ float bias_s[64];
    unsigned short* lW = (unsigned short*)lWv;

    const int tid  = threadIdx.x;
    const int lane = tid & 63;
    const int wid  = tid >> 6;
    const int lc   = lane & 15;
    const int g    = lane >> 4;

    const int n  = blockIdx.x / PB;
    const int sp = blockIdx.x % PB;
    const float* xn = x + (size_t)n * (C_DIM * S_PIX) + sp * SPB;
    const int cq = wid * 32;
    const int sl = wid*16 + lc;

    // stage W fragments + bias table (regular loads, once per block)
    #pragma unroll
    for (int it = 0; it < 8; ++it)
        lWv[it*256 + tid] = ((const f32x4*)wf)[it*256 + tid];
    if (tid < 64) {
        int gg = tid >> 4, r = tid & 15;
        bias_s[tid] = bias[16*(r >> 2) + 4*gg + (r & 3)];
    }

    f32x4 accV[4][2];
    #pragma unroll
    for (int m = 0; m < 4; ++m) { accV[m][0] = (f32x4)0.f; accV[m][1] = (f32x4)0.f; }
    float asum_acc[16];
    #pragma unroll
    for (int i = 0; i < 16; ++i) asum_acc[i] = 0.f;

    // ---- async stage of chunk 0 into buf 0 ----
    // wave stages rows [32*wid .. +31]; 8 instrs x (4 rows x 64B swizzled slots)
    {
        const int r0 = wid*32;
        #pragma unroll
        for (int i2 = 0; i2 < 8; ++i2) {
            int row = r0 + i2*4 + (lane>>4);
            const float* gp = xn + (size_t)row * S_PIX + 4*((lane&15) ^ KXOR(row));
            gll16(gp, &Xs[0][(r0 + i2*4) * 64]);
        }
    }
    asm volatile("s_waitcnt vmcnt(0)" ::: "memory");
    __syncthreads();

    int buf = 0;
    for (int ch = 0; ch < NCHK; ++ch) {
        float* Xb = &Xs[buf][0];

        // ---- fire-and-forget stage of chunk ch+1 into buf^1 ----
        if (ch + 1 < NCHK) {
            const int r0 = wid*32;
            float* Xn1 = &Xs[buf^1][0];
            #pragma unroll
            for (int i2 = 0; i2 < 8; ++i2) {
                int row = r0 + i2*4 + (lane>>4);
                const float* gp = xn + (size_t)row * S_PIX + (ch+1)*CHK
                                + 4*((lane&15) ^ KXOR(row));
                gll16(gp, &Xn1[(r0 + i2*4) * 64]);
            }
        }

        // ================= Phase A: GEMM1 + softmax (wave's 16-pixel slice) ==========
        float ss = 0.f;
        bf16x8 bh[4], bl[4];
        #pragma unroll
        for (int t = 0; t < 4; ++t) {
            float xv[8];
            #pragma unroll
            for (int j = 0; j < 8; ++j) {
                int c = 32*t + 4*j + g;                       // kdim remap (matches k_prep)
                xv[j] = Xb[c*64 + 4*((sl>>2) ^ KXOR(c)) + (sl&3)];
            }
            #pragma unroll
            for (int j = 0; j < 8; ++j) ss = fmaf(xv[j], xv[j], ss);
            cvt8(xv, bh[t], bl[t]);
        }

        f32x4 accL[4];
        #pragma unroll
        for (int m = 0; m < 4; ++m) accL[m] = (f32x4)0.f;
        #pragma unroll
        for (int t = 0; t < 4; ++t) {
            #pragma unroll
            for (int m = 0; m < 4; ++m) {
                bf16x8 ah = *(const bf16x8*)&lW[((m*4 + t)*64 + lane)*8];
                bf16x8 al = *(const bf16x8*)&lW[((16 + m*4 + t)*64 + lane)*8];
                accL[m] = __builtin_amdgcn_mfma_f32_16x16x32_bf16(ah, bh[t], accL[m], 0,0,0);
                accL[m] = __builtin_amdgcn_mfma_f32_16x16x32_bf16(ah, bl[t], accL[m], 0,0,0);
                accL[m] = __builtin_amdgcn_mfma_f32_16x16x32_bf16(al, bh[t], accL[m], 0,0,0);
            }
        }

        // softmax over k=64
        ss += __shfl_xor(ss, 16); ss += __shfl_xor(ss, 32);
        float rnorm = 1.0f / fmaxf(sqrtf(ss), 1e-12f);

        const f32x4* bt = (const f32x4*)&bias_s[g*16];
        float e[16]; float mx = -1e30f;
        #pragma unroll
        for (int m = 0; m < 4; ++m) {
            f32x4 b4 = bt[m];
            #pragma unroll
            for (int jj = 0; jj < 4; ++jj) {
                float t2 = fmaf(accL[m][jj], rnorm, b4[jj]);
                e[m*4+jj] = t2;
                mx = fmaxf(mx, t2);
            }
        }
        mx = fmaxf(mx, __shfl_xor(mx, 16)); mx = fmaxf(mx, __shfl_xor(mx, 32));
        float sm = 0.f;
        #pragma unroll
        for (int i = 0; i < 16; ++i) { e[i] = __expf(e[i] - mx); sm += e[i]; }
        sm += __shfl_xor(sm, 16); sm += __shfl_xor(sm, 32);
        float inv = 1.0f / sm;

        // a' = a*rnorm -> hi/lo bf16 -> aS
        #pragma unroll
        for (int m = 0; m < 4; ++m)
            #pragma unroll
            for (int jj = 0; jj < 4; ++jj) {
                float a = e[m*4+jj] * inv;
                asum_acc[m*4+jj] += a;
                float ap = a * rnorm;
                unsigned u = __float_as_uint(ap);
                float r = ap - __uint_as_float(u & 0xffff0000u);
                int ix = (16*m + 4*g + jj)*SROW + sl;
                aS[ix]       = (unsigned short)(u >> 16);
                aS[ASZ + ix] = (unsigned short)(__float_as_uint(r) >> 16);
            }
        __syncthreads();   // a' tile complete (X[buf] reads unaffected)

        // ================= Phase B: GEMM2 (wave's 32-c slice) ========================
        #pragma unroll
        for (int ks = 0; ks < 2; ++ks) {
            bf16x8 Ah[4], Al[4];
            #pragma unroll
            for (int m = 0; m < 4; ++m) {
                int off = (16*m + lc)*SROW + ks*32 + 8*g;
                Ah[m] = *(const bf16x8*)&aS[off];
                Al[m] = *(const bf16x8*)&aS[ASZ + off];
            }
            #pragma unroll
            for (int nn = 0; nn < 2; ++nn) {
                int c  = cq + nn*16 + lc;
                int s0 = 8*ks + 2*g;                          // original 16B-slot
                float4 f0 = *(const float4*)&Xb[c*64 + 4*((s0)   ^ KXOR(c))];
                float4 f1 = *(const float4*)&Xb[c*64 + 4*((s0+1) ^ KXOR(c))];
                float xv[8] = {f0.x,f0.y,f0.z,f0.w,f1.x,f1.y,f1.z,f1.w};
                bf16x8 xh, xl;
                cvt8(xv, xh, xl);
                #pragma unroll
                for (int m = 0; m < 4; ++m) {
                    accV[m][nn] = __builtin_amdgcn_mfma_f32_16x16x32_bf16(Ah[m], xh, accV[m][nn], 0,0,0);
                    accV[m][nn] = __builtin_amdgcn_mfma_f32_16x16x32_bf16(Ah[m], xl, accV[m][nn], 0,0,0);
                    accV[m][nn] = __builtin_amdgcn_mfma_f32_16x16x32_bf16(Al[m], xh, accV[m][nn], 0,0,0);
                }
            }
        }

        // drain next-chunk stage, release aS + X[buf^1]
        asm volatile("s_waitcnt vmcnt(0)" ::: "memory");
        __syncthreads();
        buf ^= 1;
    }

    // ---- epilogue: vlad partials -> global atomics ----
    float* vb = vlad + (size_t)n * (K_CL * C_DIM);
    #pragma unroll
    for (int m = 0; m < 4; ++m)
        #pragma unroll
        for (int nn = 0; nn < 2; ++nn)
            #pragma unroll
            for (int jj = 0; jj < 4; ++jj)
                atomicAdd(&vb[(16*m + 4*g + jj)*C_DIM + cq + nn*16 + lc],
                          accV[m][nn][jj]);

    // ---- asum: 16-lane butterfly (lanes sharing g), then atomics ----
    #pragma unroll
    for (int i = 0; i < 16; ++i) {
        float v = asum_acc[i];
        v += __shfl_xor(v, 1); v += __shfl_xor(v, 2);
        v += __shfl_xor(v, 4); v += __shfl_xor(v, 8);
        asum_acc[i] = v;
    }
    if (lc == 0) {
        #pragma unroll
        for (int m = 0; m < 4; ++m)
            #pragma unroll
            for (int jj = 0; jj < 4; ++jj)
                atomicAdd(&asum[n*K_CL + 16*m + 4*g + jj], asum_acc[m*4+jj]);
    }
}

// ---- kernel 2: subtract a-sum*centroid, intra-norm, global norm ----
__global__ __launch_bounds__(256)
void k_final(float* __restrict__ vlad,          // [N][K*C] in/out (= d_out)
             const float* __restrict__ asum,    // [N][K]
             const float* __restrict__ cent)    // [K][C]
{
    __shared__ float v[K_CL * 132];
    __shared__ float red[K_CL][4];
    __shared__ float rin[K_CL];
    __shared__ float rtot_s;
    const int tid = threadIdx.x;
    const int n   = blockIdx.x;
    float* vb = vlad + (size_t)n * (K_CL * C_DIM);
    const float* as = asum + n * K_CL;

    for (int i = tid; i < K_CL*C_DIM; i += 256) {
        int k = i >> 7, c = i & 127;
        v[k*132 + c] = vb[i] - as[k] * cent[i];
    }
    __syncthreads();
    {
        int k = tid >> 2, p = tid & 3;
        float s2 = 0.f;
        #pragma unroll
        for (int u = 0; u < 32; ++u) { float t = v[k*132 + (u<<2) + p]; s2 = fmaf(t, t, s2); }
        red[k][p] = s2;
    }
    __syncthreads();
    if (tid < K_CL) {
        float s2 = red[tid][0] + red[tid][1] + red[tid][2] + red[tid][3];
        float r  = 1.0f / fmaxf(sqrtf(s2), 1e-12f);
        rin[tid] = r;
        red[tid][0] = s2 * r * r;
    }
    __syncthreads();
    if (tid < 64) {
        float t = red[tid][0];
        t += __shfl_xor(t, 32); t += __shfl_xor(t, 16); t += __shfl_xor(t, 8);
        t += __shfl_xor(t, 4);  t += __shfl_xor(t, 2);  t += __shfl_xor(t, 1);
        if (tid == 0) rtot_s = 1.0f / fmaxf(sqrtf(t), 1e-12f);
    }
    __syncthreads();
    float rt = rtot_s;
    for (int i = tid; i < K_CL*C_DIM; i += 256) {
        vb[i] = v[(i>>7)*132 + (i&127)] * rin[i>>7] * rt;
    }
}

extern "C" void kernel_launch(void* const* d_in, const int* in_sizes, int n_in,
                              void* d_out, int out_size, void* d_ws, size_t ws_size,
                              hipStream_t stream) {
    const float* x    = (const float*)d_in[0];
    const float* w    = (const float*)d_in[1];
    const float* b    = (const float*)d_in[2];
    const float* cent = (const float*)d_in[3];
    float* out = (float*)d_out;
    unsigned short* wf = (unsigned short*)d_ws;           // 32KB
    float* asum = (float*)((char*)d_ws + 32768);          // [N][K]

    hipMemsetAsync(out,  0, (size_t)N_IMG * K_CL * C_DIM * sizeof(float), stream);
    hipMemsetAsync(asum, 0, (size_t)N_IMG * K_CL * sizeof(float), stream);

    k_prep<<<32, 256, 0, stream>>>(w, wf);
    k_main<<<N_IMG * PB, 256, 0, stream>>>(x, wf, b, out, asum);
    k_final<<<N_IMG, 256, 0, stream>>>(out, asum, cent);
}

// Round 5
// 146.593 us; speedup vs baseline: 1.6202x; 1.0274x over previous
//
#include <hip/hip_runtime.h>
#include <math.h>

#define N_IMG 128
#define C_DIM 128
#define K_CL  64
#define S_PIX 4096
#define PB    8                 // blocks per image
#define SPB   (S_PIX/PB)        // 512 pixels per block
#define CHK   64                // pixels per chunk
#define NCHK  (SPB/CHK)         // 8
#define SROW  72                // a' row stride (bf16 elems) = 144B
#define ASZ   (K_CL*SROW)       // one a' plane

// 16B-slot XOR swizzle key for the X tile (involution; applied to global src AND reads)
#define KXOR(c) ((((c)&3)<<2) | (((c)>>2)&3))

typedef __attribute__((ext_vector_type(8))) short bf16x8;
typedef __attribute__((ext_vector_type(4))) float f32x4;

__device__ __forceinline__ unsigned short f2bf_rn(float v) {
    unsigned u = __float_as_uint(v);
    unsigned r = u + 0x7fffu + ((u >> 16) & 1u);
    return (unsigned short)(r >> 16);
}
__device__ __forceinline__ float bf2f(unsigned short h) {
    return __uint_as_float(((unsigned)h) << 16);
}

// truncation hi/lo split of 8 floats -> two bf16x8, packed via v_perm
__device__ __forceinline__ void cvt8(const float* v, bf16x8& h, bf16x8& l) {
    union { unsigned w[4]; bf16x8 v8; } H, L;
    #pragma unroll
    for (int p = 0; p < 4; ++p) {
        unsigned u0 = __float_as_uint(v[2*p]);
        unsigned u1 = __float_as_uint(v[2*p+1]);
        float r0 = v[2*p]   - __uint_as_float(u0 & 0xffff0000u);
        float r1 = v[2*p+1] - __uint_as_float(u1 & 0xffff0000u);
        H.w[p] = __builtin_amdgcn_perm(u1, u0, 0x07060302u);
        L.w[p] = __builtin_amdgcn_perm(__float_as_uint(r1), __float_as_uint(r0), 0x07060302u);
    }
    h = H.v8; l = L.v8;
}

// async global->LDS, 16B per lane, lane writes lds + lane*16 (linear)
__device__ __forceinline__ void gll16(const float* g, float* l) {
    __builtin_amdgcn_global_load_lds(
        (const __attribute__((address_space(1))) unsigned int*)(g),
        (__attribute__((address_space(3))) unsigned int*)(l),
        16, 0, 0);
}

// ---- kernel 0: W [K][C] fp32 -> pre-fragmented hi/lo bf16 A-fragments ----
// kdim map: MFMA kdim position p=8g+j (g=lane>>4) <-> channel c = 32t + 4j + g
__global__ void k_prep(const float* __restrict__ w, unsigned short* __restrict__ wf) {
    int i = blockIdx.x * 256 + threadIdx.x;          // 8192
    int j = i & 7, l = (i >> 3) & 63, t = (i >> 9) & 3, m = (i >> 11) & 3;
    int k = 16*m + (l & 15);
    int c = 32*t + 4*j + (l >> 4);
    float v = w[k * C_DIM + c];
    unsigned short h = f2bf_rn(v);
    wf[i]        = h;
    wf[8192 + i] = f2bf_rn(v - bf2f(h));
}

// ---- clear kernel: zero vlad accumulator (4MB) + asum (32KB) ----
__global__ void k_clear(float4* __restrict__ out4, float4* __restrict__ asum4) {
    int i = blockIdx.x * 256 + threadIdx.x;
    f32x4 z = (f32x4)0.f;
    if (i < (N_IMG*K_CL*C_DIM)/4) out4[i] = *(float4*)&z;
    if (i < (N_IMG*K_CL)/4)       asum4[i] = *(float4*)&z;
}

// ---- kernel 1: fused GEMM1(MFMA) -> softmax -> GEMM2(MFMA), 8 waves ----
__global__ __launch_bounds__(512)
void k_main(const float* __restrict__ x,              // [N][C][S]
            const unsigned short* __restrict__ wf,    // [2][16][64][8] bf16 bits
            const float* __restrict__ bias,           // [K]
            float* __restrict__ vlad,                 // [N][K][C] accumulator (= d_out)
            float* __restrict__ asum)                 // [N][K]
{
    __shared__ float Xs[2][C_DIM*CHK];                // 64KB: x chunk tile, dbuf, swizzled
    __shared__ unsigned short aS[2*ASZ];              // 18KB: a' tile (hi/lo planes)
    __shared__ float2 red[4][2][16];                  // 1KB: softmax (max,sum) exchange

    const int tid  = threadIdx.x;
    const int lane = tid & 63;
    const int wid  = tid >> 6;            // 0..7
    const int lc   = lane & 15;
    const int g    = lane >> 4;

    const int p  = wid & 3;               // phase A: px-tile
    const int mh = wid >> 2;              // phase A: k-half (2 m-tiles)
    const int px = p*16 + lc;
    const int cq = wid * 16;              // phase B: c-slice

    const int n  = blockIdx.x / PB;
    const int sp = blockIdx.x % PB;
    const float* xn = x + (size_t)n * (C_DIM * S_PIX) + sp * SPB;

    // ---- W fragments for this wave's k-half into REGISTERS ----
    bf16x8 Wh[2][4], Wl[2][4];
    #pragma unroll
    for (int mm = 0; mm < 2; ++mm)
        #pragma unroll
        for (int t = 0; t < 4; ++t) {
            int m = 2*mh + mm;
            Wh[mm][t] = *(const bf16x8*)&wf[((m*4 + t)*64 + lane)*8];
            Wl[mm][t] = *(const bf16x8*)&wf[((16 + m*4 + t)*64 + lane)*8];
        }
    // bias: 8 per-lane values k = 32mh+16mm+4g+jj
    f32x4 bias_r[2];
    #pragma unroll
    for (int mm = 0; mm < 2; ++mm)
        bias_r[mm] = *(const f32x4*)&bias[32*mh + 16*mm + 4*g];

    f32x4 accV[4];
    #pragma unroll
    for (int m = 0; m < 4; ++m) accV[m] = (f32x4)0.f;
    float asum_acc[8];
    #pragma unroll
    for (int i = 0; i < 8; ++i) asum_acc[i] = 0.f;

    // ---- async stage: wave stages 16 rows (r0..r0+15), 4 gll16 ----
    const int r0 = wid * 16;
    const int srow = r0 + (lane >> 4);            // this lane's row offset base
    {
        #pragma unroll
        for (int i2 = 0; i2 < 4; ++i2) {
            int row = r0 + i2*4 + (lane >> 4);
            const float* gp = xn + (size_t)row * S_PIX + 4*((lane & 15) ^ KXOR(row));
            gll16(gp, &Xs[0][(r0 + i2*4) * 64]);
        }
    }
    asm volatile("s_waitcnt vmcnt(0)" ::: "memory");
    __syncthreads();

    int buf = 0;
    for (int ch = 0; ch < NCHK; ++ch) {
        float* Xb = &Xs[buf][0];

        // ---- fire-and-forget stage of chunk ch+1 ----
        if (ch + 1 < NCHK) {
            float* Xn1 = &Xs[buf^1][0];
            #pragma unroll
            for (int i2 = 0; i2 < 4; ++i2) {
                int row = r0 + i2*4 + (lane >> 4);
                const float* gp = xn + (size_t)row * S_PIX + (ch+1)*CHK
                                + 4*((lane & 15) ^ KXOR(row));
                gll16(gp, &Xn1[(r0 + i2*4) * 64]);
            }
        }

        // ================= Phase A: GEMM1 (2 m-tiles) + softmax =================
        float ss = 0.f;
        f32x4 accL[2];
        accL[0] = (f32x4)0.f; accL[1] = (f32x4)0.f;
        #pragma unroll
        for (int t = 0; t < 4; ++t) {
            float xv[8];
            #pragma unroll
            for (int j = 0; j < 8; ++j) {
                int c = 32*t + 4*j + g;                       // kdim remap (matches k_prep)
                xv[j] = Xb[c*64 + 4*((px>>2) ^ KXOR(c)) + (px&3)];
            }
            #pragma unroll
            for (int j = 0; j < 8; ++j) ss = fmaf(xv[j], xv[j], ss);
            bf16x8 xh, xl;
            cvt8(xv, xh, xl);
            #pragma unroll
            for (int mm = 0; mm < 2; ++mm) {
                accL[mm] = __builtin_amdgcn_mfma_f32_16x16x32_bf16(Wh[mm][t], xh, accL[mm], 0,0,0);
                accL[mm] = __builtin_amdgcn_mfma_f32_16x16x32_bf16(Wh[mm][t], xl, accL[mm], 0,0,0);
                accL[mm] = __builtin_amdgcn_mfma_f32_16x16x32_bf16(Wl[mm][t], xh, accL[mm], 0,0,0);
            }
        }
        ss += __shfl_xor(ss, 16); ss += __shfl_xor(ss, 32);
        float rnorm = 1.0f / fmaxf(sqrtf(ss), 1e-12f);

        // local (this k-half) max + expsum
        float e[8]; float mx = -1e30f;
        #pragma unroll
        for (int mm = 0; mm < 2; ++mm)
            #pragma unroll
            for (int jj = 0; jj < 4; ++jj) {
                float t2 = fmaf(accL[mm][jj], rnorm, bias_r[mm][jj]);
                e[mm*4+jj] = t2;
                mx = fmaxf(mx, t2);
            }
        mx = fmaxf(mx, __shfl_xor(mx, 16)); mx = fmaxf(mx, __shfl_xor(mx, 32));
        float sm = 0.f;
        #pragma unroll
        for (int i = 0; i < 8; ++i) { e[i] = __expf(e[i] - mx); sm += e[i]; }
        sm += __shfl_xor(sm, 16); sm += __shfl_xor(sm, 32);
        if (g == 0) red[p][mh][lc] = make_float2(mx, sm);
        __syncthreads();                                  // barrier 1: (mx,sm) pairs

        // online-softmax combine with sibling k-half
        float2 sib = red[p][mh^1][lc];
        float M  = fmaxf(mx, sib.x);
        float f  = __expf(mx - M);
        float fs = __expf(sib.x - M);
        float S  = fmaf(sm, f, sib.y * fs);
        float coef  = f / S;                              // a = e * coef
        float coefr = coef * rnorm;                       // a' = a * rnorm

        // write a' hi/lo to aS; accumulate asum (raw a)
        #pragma unroll
        for (int mm = 0; mm < 2; ++mm)
            #pragma unroll
            for (int jj = 0; jj < 4; ++jj) {
                float ev = e[mm*4+jj];
                asum_acc[mm*4+jj] += ev * coef;
                float ap = ev * coefr;
                unsigned u = __float_as_uint(ap);
                float r = ap - __uint_as_float(u & 0xffff0000u);
                int k = 32*mh + 16*mm + 4*g + jj;
                int ix = k*SROW + px;
                aS[ix]       = (unsigned short)(u >> 16);
                aS[ASZ + ix] = (unsigned short)(__float_as_uint(r) >> 16);
            }
        __syncthreads();                                  // barrier 2: aS ready

        // ================= Phase B: GEMM2 (wave's 16-c slice) ===================
        #pragma unroll
        for (int ks = 0; ks < 2; ++ks) {
            bf16x8 Ah[4], Al[4];
            #pragma unroll
            for (int m = 0; m < 4; ++m) {
                int off = (16*m + lc)*SROW + ks*32 + 8*g;
                Ah[m] = *(const bf16x8*)&aS[off];
                Al[m] = *(const bf16x8*)&aS[ASZ + off];
            }
            int c  = cq + lc;
            int s0 = 8*ks + 2*g;
            float4 f0 = *(const float4*)&Xb[c*64 + 4*((s0)   ^ KXOR(c))];
            float4 f1 = *(const float4*)&Xb[c*64 + 4*((s0+1) ^ KXOR(c))];
            float xv[8] = {f0.x,f0.y,f0.z,f0.w,f1.x,f1.y,f1.z,f1.w};
            bf16x8 xh, xl;
            cvt8(xv, xh, xl);
            #pragma unroll
            for (int m = 0; m < 4; ++m) {
                accV[m] = __builtin_amdgcn_mfma_f32_16x16x32_bf16(Ah[m], xh, accV[m], 0,0,0);
                accV[m] = __builtin_amdgcn_mfma_f32_16x16x32_bf16(Ah[m], xl, accV[m], 0,0,0);
                accV[m] = __builtin_amdgcn_mfma_f32_16x16x32_bf16(Al[m], xh, accV[m], 0,0,0);
            }
        }

        // drain next-chunk stage, release aS + X[buf^1]
        asm volatile("s_waitcnt vmcnt(0)" ::: "memory");
        __syncthreads();                                  // barrier 3
        buf ^= 1;
    }

    // ---- epilogue: vlad partials -> global atomics ----
    float* vb = vlad + (size_t)n * (K_CL * C_DIM);
    #pragma unroll
    for (int m = 0; m < 4; ++m)
        #pragma unroll
        for (int jj = 0; jj < 4; ++jj)
            atomicAdd(&vb[(16*m + 4*g + jj)*C_DIM + cq + lc], accV[m][jj]);

    // ---- asum: 16-lane butterfly over lc, then atomics ----
    #pragma unroll
    for (int i = 0; i < 8; ++i) {
        float v = asum_acc[i];
        v += __shfl_xor(v, 1); v += __shfl_xor(v, 2);
        v += __shfl_xor(v, 4); v += __shfl_xor(v, 8);
        asum_acc[i] = v;
    }
    if (lc == 0) {
        #pragma unroll
        for (int mm = 0; mm < 2; ++mm)
            #pragma unroll
            for (int jj = 0; jj < 4; ++jj)
                atomicAdd(&asum[n*K_CL + 32*mh + 16*mm + 4*g + jj], asum_acc[mm*4+jj]);
    }
}

// ---- kernel 2: subtract a-sum*centroid, intra-norm, global norm ----
__global__ __launch_bounds__(256)
void k_final(float* __restrict__ vlad,          // [N][K*C] in/out (= d_out)
             const float* __restrict__ asum,    // [N][K]
             const float* __restrict__ cent)    // [K][C]
{
    __shared__ float v[K_CL * 132];
    __shared__ float red[K_CL][4];
    __shared__ float rin[K_CL];
    __shared__ float rtot_s;
    const int tid = threadIdx.x;
    const int n   = blockIdx.x;
    float* vb = vlad + (size_t)n * (K_CL * C_DIM);
    const float* as = asum + n * K_CL;

    for (int i = tid; i < K_CL*C_DIM; i += 256) {
        int k = i >> 7, c = i & 127;
        v[k*132 + c] = vb[i] - as[k] * cent[i];
    }
    __syncthreads();
    {
        int k = tid >> 2, p = tid & 3;
        float s2 = 0.f;
        #pragma unroll
        for (int u = 0; u < 32; ++u) { float t = v[k*132 + (u<<2) + p]; s2 = fmaf(t, t, s2); }
        red[k][p] = s2;
    }
    __syncthreads();
    if (tid < K_CL) {
        float s2 = red[tid][0] + red[tid][1] + red[tid][2] + red[tid][3];
        float r  = 1.0f / fmaxf(sqrtf(s2), 1e-12f);
        rin[tid] = r;
        red[tid][0] = s2 * r * r;
    }
    __syncthreads();
    if (tid < 64) {
        float t = red[tid][0];
        t += __shfl_xor(t, 32); t += __shfl_xor(t, 16); t += __shfl_xor(t, 8);
        t += __shfl_xor(t, 4);  t += __shfl_xor(t, 2);  t += __shfl_xor(t, 1);
        if (tid == 0) rtot_s = 1.0f / fmaxf(sqrtf(t), 1e-12f);
    }
    __syncthreads();
    float rt = rtot_s;
    for (int i = tid; i < K_CL*C_DIM; i += 256) {
        vb[i] = v[(i>>7)*132 + (i&127)] * rin[i>>7] * rt;
    }
}

extern "C" void kernel_launch(void* const* d_in, const int* in_sizes, int n_in,
                              void* d_out, int out_size, void* d_ws, size_t ws_size,
                              hipStream_t stream) {
    const float* x    = (const float*)d_in[0];
    const float* w    = (const float*)d_in[1];
    const float* b    = (const float*)d_in[2];
    const float* cent = (const float*)d_in[3];
    float* out = (float*)d_out;
    unsigned short* wf = (unsigned short*)d_ws;           // 32KB
    float* asum = (float*)((char*)d_ws + 32768);          // [N][K]

    k_clear<<<(N_IMG*K_CL*C_DIM/4 + 255)/256, 256, 0, stream>>>(
        (float4*)out, (float4*)asum);
    k_prep<<<32, 256, 0, stream>>>(w, wf);
    k_main<<<N_IMG * PB, 512, 0, stream>>>(x, wf, b, out, asum);
    k_final<<<N_IMG, 256, 0, stream>>>(out, asum, cent);
}

// Round 6
// 128.421 us; speedup vs baseline: 1.8494x; 1.1415x over previous
//
#include <hip/hip_runtime.h>
#include <math.h>

#define N_IMG 128
#define C_DIM 128
#define K_CL  64
#define S_PIX 4096
#define PB    8                 // blocks per image
#define SPB   (S_PIX/PB)        // 512 pixels per block
#define CHK   64                // pixels per chunk
#define NCHK  (SPB/CHK)         // 8
#define SROW  72                // a' row stride (bf16 elems) = 144B
#define ASZ   (K_CL*SROW)       // one a' plane
#define NBUF  3                 // X staging buffers (2-deep prefetch)

// 16B-slot XOR swizzle key for the X tile (involution; applied to global src AND reads)
#define KXOR(c) ((((c)&3)<<2) | (((c)>>2)&3))

typedef __attribute__((ext_vector_type(8))) short bf16x8;
typedef __attribute__((ext_vector_type(4))) float f32x4;

__device__ __forceinline__ unsigned short f2bf_rn(float v) {
    unsigned u = __float_as_uint(v);
    unsigned r = u + 0x7fffu + ((u >> 16) & 1u);
    return (unsigned short)(r >> 16);
}
__device__ __forceinline__ float bf2f(unsigned short h) {
    return __uint_as_float(((unsigned)h) << 16);
}

// truncation hi/lo split of 8 floats -> two bf16x8, packed via v_perm
__device__ __forceinline__ void cvt8(const float* v, bf16x8& h, bf16x8& l) {
    union { unsigned w[4]; bf16x8 v8; } H, L;
    #pragma unroll
    for (int p = 0; p < 4; ++p) {
        unsigned u0 = __float_as_uint(v[2*p]);
        unsigned u1 = __float_as_uint(v[2*p+1]);
        float r0 = v[2*p]   - __uint_as_float(u0 & 0xffff0000u);
        float r1 = v[2*p+1] - __uint_as_float(u1 & 0xffff0000u);
        H.w[p] = __builtin_amdgcn_perm(u1, u0, 0x07060302u);
        L.w[p] = __builtin_amdgcn_perm(__float_as_uint(r1), __float_as_uint(r0), 0x07060302u);
    }
    h = H.v8; l = L.v8;
}

// async global->LDS, 16B per lane, lane writes lds + lane*16 (linear)
__device__ __forceinline__ void gll16(const float* g, float* l) {
    __builtin_amdgcn_global_load_lds(
        (const __attribute__((address_space(1))) unsigned int*)(g),
        (__attribute__((address_space(3))) unsigned int*)(l),
        16, 0, 0);
}

// ---- kernel 0: W [K][C] fp32 -> pre-fragmented hi/lo bf16 A-fragments ----
// kdim map: MFMA kdim position p=8g+j (g=lane>>4) <-> channel c = 32t + 4j + g
__global__ void k_prep(const float* __restrict__ w, unsigned short* __restrict__ wf) {
    int i = blockIdx.x * 256 + threadIdx.x;          // 8192
    int j = i & 7, l = (i >> 3) & 63, t = (i >> 9) & 3, m = (i >> 11) & 3;
    int k = 16*m + (l & 15);
    int c = 32*t + 4*j + (l >> 4);
    float v = w[k * C_DIM + c];
    unsigned short h = f2bf_rn(v);
    wf[i]        = h;
    wf[8192 + i] = f2bf_rn(v - bf2f(h));
}

// ---- clear kernel: zero vlad accumulator (4MB) + asum (32KB) ----
__global__ void k_clear(float4* __restrict__ out4, float4* __restrict__ asum4) {
    int i = blockIdx.x * 256 + threadIdx.x;
    f32x4 z = (f32x4)0.f;
    if (i < (N_IMG*K_CL*C_DIM)/4) out4[i] = *(float4*)&z;
    if (i < (N_IMG*K_CL)/4)       asum4[i] = *(float4*)&z;
}

// ---- kernel 1: fused GEMM1(MFMA) -> softmax -> GEMM2(MFMA), raw-barrier pipeline ----
__global__ __launch_bounds__(512, 1)
void k_main(const float* __restrict__ x,              // [N][C][S]
            const unsigned short* __restrict__ wf,    // [2][16][64][8] bf16 bits
            const float* __restrict__ bias,           // [K]
            float* __restrict__ vlad,                 // [N][K][C] accumulator (= d_out)
            float* __restrict__ asum)                 // [N][K]
{
    __shared__ float Xs[NBUF][C_DIM*CHK/2];           // 3 x 32KB... (see note below)
    // NOTE: C_DIM*CHK floats = 8192 per buffer; declared flat below to keep 32KB each.
    __shared__ float Xs2[NBUF][C_DIM*CHK - C_DIM*CHK/2]; // second half (contiguity not required across buffers)
    __shared__ unsigned short aS[2*ASZ];              // 18KB: a' tile (hi/lo planes)
    __shared__ float redS[4][2][16];                  // 512B: softmax sum exchange

    // Accessor that treats buffer b as contiguous 8192 floats:
    // rows 0..63 live in Xs[b], rows 64..127 in Xs2[b] (each 4096 floats).
    auto XP = [&](int b, int idx) -> float* {
        return (idx < 4096) ? &Xs[b][idx] : &Xs2[b][idx - 4096];
    };

    const int tid  = threadIdx.x;
    const int lane = tid & 63;
    const int wid  = tid >> 6;            // 0..7
    const int lc   = lane & 15;
    const int g    = lane >> 4;

    const int p  = wid & 3;               // phase A: px-tile
    const int mh = wid >> 2;              // phase A: k-half (2 m-tiles)
    const int px = p*16 + lc;
    const int cq = wid * 16;              // phase B: c-slice

    const int n  = blockIdx.x / PB;
    const int sp = blockIdx.x % PB;
    const float* xn = x + (size_t)n * (C_DIM * S_PIX) + sp * SPB;

    // ---- W fragments for this wave's k-half into REGISTERS (anchored) ----
    bf16x8 Wh[2][4], Wl[2][4];
    #pragma unroll
    for (int mm = 0; mm < 2; ++mm)
        #pragma unroll
        for (int t = 0; t < 4; ++t) {
            int m = 2*mh + mm;
            Wh[mm][t] = *(const bf16x8*)&wf[((m*4 + t)*64 + lane)*8];
            Wl[mm][t] = *(const bf16x8*)&wf[((16 + m*4 + t)*64 + lane)*8];
        }
    #pragma unroll
    for (int mm = 0; mm < 2; ++mm)
        #pragma unroll
        for (int t = 0; t < 4; ++t) {
            asm volatile("" : "+v"(Wh[mm][t]));
            asm volatile("" : "+v"(Wl[mm][t]));
        }

    f32x4 bias_r[2];
    #pragma unroll
    for (int mm = 0; mm < 2; ++mm)
        bias_r[mm] = *(const f32x4*)&bias[32*mh + 16*mm + 4*g];

    f32x4 accV[4];
    #pragma unroll
    for (int m = 0; m < 4; ++m) accV[m] = (f32x4)0.f;
    float asum_acc[8];
    #pragma unroll
    for (int i = 0; i < 8; ++i) asum_acc[i] = 0.f;

    const int r0 = wid * 16;              // this wave's 16 staged rows

    // stage chunk t into buffer b (4 gll16 per wave, fire-and-forget)
    auto STAGE = [&](int t, int b) {
        #pragma unroll
        for (int i2 = 0; i2 < 4; ++i2) {
            int rowbase = r0 + i2*4;
            int row = rowbase + (lane >> 4);
            const float* gp = xn + (size_t)row * S_PIX + t*CHK
                            + 4*((lane & 15) ^ KXOR(row));
            gll16(gp, XP(b, rowbase * 64));
        }
    };

    // ---- prologue: 2-deep prefetch ----
    STAGE(0, 0);
    STAGE(1, 1);
    asm volatile("s_waitcnt vmcnt(4)" ::: "memory");   // chunk 0 complete
    __builtin_amdgcn_s_barrier();
    __builtin_amdgcn_sched_barrier(0);

    #pragma unroll
    for (int ch = 0; ch < NCHK; ++ch) {
        const int rb = ch % NBUF;

        // ---- fire-and-forget stage of chunk ch+2 ----
        if (ch + 2 < NCHK) STAGE(ch + 2, (ch + 2) % NBUF);

        // ================= Phase A: GEMM1 (2 m-tiles) + softmax =================
        float ss = 0.f;
        f32x4 accL[2];
        accL[0] = (f32x4)0.f; accL[1] = (f32x4)0.f;
        #pragma unroll
        for (int t = 0; t < 4; ++t) {
            float xv[8];
            #pragma unroll
            for (int j = 0; j < 8; ++j) {
                int c = 32*t + 4*j + g;                       // kdim remap (matches k_prep)
                xv[j] = *XP(rb, c*64 + 4*((px>>2) ^ KXOR(c)) + (px&3));
            }
            #pragma unroll
            for (int j = 0; j < 8; ++j) ss = fmaf(xv[j], xv[j], ss);
            bf16x8 xh, xl;
            cvt8(xv, xh, xl);
            #pragma unroll
            for (int mm = 0; mm < 2; ++mm) {
                accL[mm] = __builtin_amdgcn_mfma_f32_16x16x32_bf16(Wh[mm][t], xh, accL[mm], 0,0,0);
                accL[mm] = __builtin_amdgcn_mfma_f32_16x16x32_bf16(Wh[mm][t], xl, accL[mm], 0,0,0);
                accL[mm] = __builtin_amdgcn_mfma_f32_16x16x32_bf16(Wl[mm][t], xh, accL[mm], 0,0,0);
            }
        }
        ss += __shfl_xor(ss, 16); ss += __shfl_xor(ss, 32);
        float rnorm = 1.0f / fmaxf(sqrtf(ss), 1e-12f);

        // no-max softmax: logits bounded (|dot|<=||w_k||~1.15, |b|<=0.5)
        float e[8]; float sm = 0.f;
        #pragma unroll
        for (int mm = 0; mm < 2; ++mm)
            #pragma unroll
            for (int jj = 0; jj < 4; ++jj) {
                float t2 = __expf(fmaf(accL[mm][jj], rnorm, bias_r[mm][jj]));
                e[mm*4+jj] = t2;
                sm += t2;
            }
        sm += __shfl_xor(sm, 16); sm += __shfl_xor(sm, 32);
        if (g == 0) redS[p][mh][lc] = sm;

        // ---- B1: red ready (LDS flush only, DMA stays in flight) ----
        asm volatile("s_waitcnt lgkmcnt(0)" ::: "memory");
        __builtin_amdgcn_s_barrier();
        __builtin_amdgcn_sched_barrier(0);

        float S = sm + redS[p][mh^1][lc];
        float coef  = 1.0f / S;
        float coefr = coef * rnorm;

        // write a' hi/lo to aS; accumulate asum (raw a)
        #pragma unroll
        for (int mm = 0; mm < 2; ++mm)
            #pragma unroll
            for (int jj = 0; jj < 4; ++jj) {
                float ev = e[mm*4+jj];
                asum_acc[mm*4+jj] += ev * coef;
                float ap = ev * coefr;
                unsigned u = __float_as_uint(ap);
                float r = ap - __uint_as_float(u & 0xffff0000u);
                int k = 32*mh + 16*mm + 4*g + jj;
                int ix = k*SROW + px;
                aS[ix]       = (unsigned short)(u >> 16);
                aS[ASZ + ix] = (unsigned short)(__float_as_uint(r) >> 16);
            }

        // ---- B2: aS ready (LDS flush only) ----
        asm volatile("s_waitcnt lgkmcnt(0)" ::: "memory");
        __builtin_amdgcn_s_barrier();
        __builtin_amdgcn_sched_barrier(0);

        // ================= Phase B: GEMM2 (wave's 16-c slice) ===================
        #pragma unroll
        for (int ks = 0; ks < 2; ++ks) {
            bf16x8 Ah[4], Al[4];
            #pragma unroll
            for (int m = 0; m < 4; ++m) {
                int off = (16*m + lc)*SROW + ks*32 + 8*g;
                Ah[m] = *(const bf16x8*)&aS[off];
                Al[m] = *(const bf16x8*)&aS[ASZ + off];
            }
            int c  = cq + lc;
            int s0 = 8*ks + 2*g;
            float4 f0 = *(const float4*)XP(rb, c*64 + 4*((s0)   ^ KXOR(c)));
            float4 f1 = *(const float4*)XP(rb, c*64 + 4*((s0+1) ^ KXOR(c)));
            float xv[8] = {f0.x,f0.y,f0.z,f0.w,f1.x,f1.y,f1.z,f1.w};
            bf16x8 xh, xl;
            cvt8(xv, xh, xl);
            #pragma unroll
            for (int m = 0; m < 4; ++m) {
                accV[m] = __builtin_amdgcn_mfma_f32_16x16x32_bf16(Ah[m], xh, accV[m], 0,0,0);
                accV[m] = __builtin_amdgcn_mfma_f32_16x16x32_bf16(Ah[m], xl, accV[m], 0,0,0);
                accV[m] = __builtin_amdgcn_mfma_f32_16x16x32_bf16(Al[m], xh, accV[m], 0,0,0);
            }
        }

        // ---- B3: chunk ch+1 staged data ready; aS + Xs[rb] released ----
        if (ch < NCHK - 1) {
            if (ch + 2 < NCHK) asm volatile("s_waitcnt vmcnt(4)" ::: "memory");
            else               asm volatile("s_waitcnt vmcnt(0)" ::: "memory");
            __builtin_amdgcn_s_barrier();
            __builtin_amdgcn_sched_barrier(0);
        }
    }

    // ---- epilogue: vlad partials -> global atomics ----
    float* vb = vlad + (size_t)n * (K_CL * C_DIM);
    #pragma unroll
    for (int m = 0; m < 4; ++m)
        #pragma unroll
        for (int jj = 0; jj < 4; ++jj)
            atomicAdd(&vb[(16*m + 4*g + jj)*C_DIM + cq + lc], accV[m][jj]);

    // ---- asum: 16-lane butterfly over lc, then atomics ----
    #pragma unroll
    for (int i = 0; i < 8; ++i) {
        float v = asum_acc[i];
        v += __shfl_xor(v, 1); v += __shfl_xor(v, 2);
        v += __shfl_xor(v, 4); v += __shfl_xor(v, 8);
        asum_acc[i] = v;
    }
    if (lc == 0) {
        #pragma unroll
        for (int mm = 0; mm < 2; ++mm)
            #pragma unroll
            for (int jj = 0; jj < 4; ++jj)
                atomicAdd(&asum[n*K_CL + 32*mh + 16*mm + 4*g + jj], asum_acc[mm*4+jj]);
    }
}

// ---- kernel 2: subtract a-sum*centroid, intra-norm, global norm ----
__global__ __launch_bounds__(256)
void k_final(float* __restrict__ vlad,          // [N][K*C] in/out (= d_out)
             const float* __restrict__ asum,    // [N][K]
             const float* __restrict__ cent)    // [K][C]
{
    __shared__ float v[K_CL * 132];
    __shared__ float red[K_CL][4];
    __shared__ float rin[K_CL];
    __shared__ float rtot_s;
    const int tid = threadIdx.x;
    const int n   = blockIdx.x;
    float* vb = vlad + (size_t)n * (K_CL * C_DIM);
    const float* as = asum + n * K_CL;

    for (int i = tid; i < K_CL*C_DIM; i += 256) {
        int k = i >> 7, c = i & 127;
        v[k*132 + c] = vb[i] - as[k] * cent[i];
    }
    __syncthreads();
    {
        int k = tid >> 2, p = tid & 3;
        float s2 = 0.f;
        #pragma unroll
        for (int u = 0; u < 32; ++u) { float t = v[k*132 + (u<<2) + p]; s2 = fmaf(t, t, s2); }
        red[k][p] = s2;
    }
    __syncthreads();
    if (tid < K_CL) {
        float s2 = red[tid][0] + red[tid][1] + red[tid][2] + red[tid][3];
        float r  = 1.0f / fmaxf(sqrtf(s2), 1e-12f);
        rin[tid] = r;
        red[tid][0] = s2 * r * r;
    }
    __syncthreads();
    if (tid < 64) {
        float t = red[tid][0];
        t += __shfl_xor(t, 32); t += __shfl_xor(t, 16); t += __shfl_xor(t, 8);
        t += __shfl_xor(t, 4);  t += __shfl_xor(t, 2);  t += __shfl_xor(t, 1);
        if (tid == 0) rtot_s = 1.0f / fmaxf(sqrtf(t), 1e-12f);
    }
    __syncthreads();
    float rt = rtot_s;
    for (int i = tid; i < K_CL*C_DIM; i += 256) {
        vb[i] = v[(i>>7)*132 + (i&127)] * rin[i>>7] * rt;
    }
}

extern "C" void kernel_launch(void* const* d_in, const int* in_sizes, int n_in,
                              void* d_out, int out_size, void* d_ws, size_t ws_size,
                              hipStream_t stream) {
    const float* x    = (const float*)d_in[0];
    const float* w    = (const float*)d_in[1];
    const float* b    = (const float*)d_in[2];
    const float* cent = (const float*)d_in[3];
    float* out = (float*)d_out;
    unsigned short* wf = (unsigned short*)d_ws;           // 32KB
    float* asum = (float*)((char*)d_ws + 32768);          // [N][K]

    k_clear<<<(N_IMG*K_CL*C_DIM/4 + 255)/256, 256, 0, stream>>>(
        (float4*)out, (float4*)asum);
    k_prep<<<32, 256, 0, stream>>>(w, wf);
    k_main<<<N_IMG * PB, 512, 0, stream>>>(x, wf, b, out, asum);
    k_final<<<N_IMG, 256, 0, stream>>>(out, asum, cent);
}